// Round 4
// baseline (536.044 us; speedup 1.0000x reference)
//
#include <hip/hip_runtime.h>

#define NB 128
#define NT 512
#define NL 256
#define BG 16            // batches per workgroup
#define NWG (NB / BG)    // 8 workgroups

typedef _Float16 h8 __attribute__((ext_vector_type(8)));
typedef _Float16 h4 __attribute__((ext_vector_type(4)));
typedef float f32x4 __attribute__((ext_vector_type(4)));

#define EAP 264                    // padded k-stride (f16 elems) for ea tile
#define SHIFT2 6.0f                // base-2 headroom shift (~ e^4.16)
#define INV_LN2 1.4426950408889634f
#define LN2 0.6931471805599453f

__device__ inline float log2_fast(float x) {
#if __has_builtin(__builtin_amdgcn_logf)
    return __builtin_amdgcn_logf(x);      // v_log_f32 (base-2)
#else
    return __log2f(x);
#endif
}
__device__ inline float exp2_fast(float x) {
#if __has_builtin(__builtin_amdgcn_exp2f)
    return __builtin_amdgcn_exp2f(x);     // v_exp_f32 (base-2)
#else
    return exp2f(x);
#endif
}

// One WG (256 thr = 4 waves) per 16 batches.
//   D(256x16) = expM(256x256, f16 A-frags in VGPRs) x EA(256x16, f16 LDS)
// then EXACT f32 log-space reconstruction (no multiplicative scale chain):
//   alpha2[i,b] = e_t[i,b]*INV_LN2 + log2(D[i,b]) + B2_prev(b)
//   EA_next     = 2^(alpha2 - B2_cur),  B2_cur = (stale exact max of alpha2) + 6
// Staleness only affects the f16 encoding range (bounded, like round 2's +4
// shift in natural log), never feeds back into alpha itself.
// Lane mapping: b = l&15, g = l>>4; A: row=l&15, k=g*8+j; B: col=l&15,
// k=g*8+j; D: col=l&15, row=g*4+reg (m89-verified).
__global__ __launch_bounds__(256, 1) void crf_forward(
    const float* __restrict__ emis,
    const float* __restrict__ trans,
    const int*   __restrict__ words,
    float*       __restrict__ bout)
{
    const int tid = threadIdx.x;
    const int l   = tid & 63;
    const int wv  = tid >> 6;
    const int g   = l >> 4;
    const int b   = l & 15;

    __shared__ _Float16 ea[2][BG][EAP];            // 2^(alpha2 - B2), dbuf
    __shared__ __align__(16) float pmaxp[2][BG][4]; // per-wave partial maxes
    __shared__ float sump[BG][16];
    __shared__ float lzb[BG];
    __shared__ int   wlds[BG * NT];

    // ---- stage this WG's word rows ----
    {
        const int4* wsrc = reinterpret_cast<const int4*>(words + blockIdx.x * (BG * NT));
        int4* wdst = reinterpret_cast<int4*>(wlds);
        #pragma unroll
        for (int c = 0; c < 8; ++c) wdst[c * 256 + tid] = wsrc[c * 256 + tid];
    }

    // ---- A-fragments: exp(trans) rows owned by this wave (128 VGPRs) ----
    h8 afr[4][8];
    #pragma unroll
    for (int T = 0; T < 4; ++T) {
        const int row = wv * 64 + T * 16 + b;
        #pragma unroll
        for (int kt = 0; kt < 8; ++kt) {
            const float* src = trans + row * NL + kt * 32 + g * 8;
            float4 v0 = *reinterpret_cast<const float4*>(src);
            float4 v1 = *reinterpret_cast<const float4*>(src + 4);
            h8 a;
            a[0] = (_Float16)__expf(v0.x); a[1] = (_Float16)__expf(v0.y);
            a[2] = (_Float16)__expf(v0.z); a[3] = (_Float16)__expf(v0.w);
            a[4] = (_Float16)__expf(v1.x); a[5] = (_Float16)__expf(v1.y);
            a[6] = (_Float16)__expf(v1.z); a[7] = (_Float16)__expf(v1.w);
            afr[T][kt] = a;
        }
    }
    __syncthreads();   // wlds visible

    // ---- t=0: alpha2_0 = e0*INV_LN2 ; EA_0 = 2^alpha2_0 (B2_0 = 0) ----
    float4 pfA[4], pfB[4];
    float B2prev = 0.f;
    {
        const int w0 = wlds[b * NT + 0];
        const float* e0 = emis + (size_t)w0 * NL + wv * 64 + g * 4;
        float vmax = -1e30f;
        #pragma unroll
        for (int T = 0; T < 4; ++T) {
            float4 v = *reinterpret_cast<const float4*>(e0 + T * 16);
            float a0 = v.x * INV_LN2, a1 = v.y * INV_LN2;
            float a2 = v.z * INV_LN2, a3 = v.w * INV_LN2;
            vmax = fmaxf(fmaxf(vmax, fmaxf(a0, a1)), fmaxf(a2, a3));
            h4 q = { (_Float16)exp2_fast(a0), (_Float16)exp2_fast(a1),
                     (_Float16)exp2_fast(a2), (_Float16)exp2_fast(a3) };
            *reinterpret_cast<h4*>(&ea[0][b][wv * 64 + T * 16 + g * 4]) = q;
        }
        vmax = fmaxf(vmax, __shfl_xor(vmax, 16));
        vmax = fmaxf(vmax, __shfl_xor(vmax, 32));
        if (g == 0) pmaxp[0][b][wv] = vmax;
        const int w1 = wlds[b * NT + 1];
        const float* e1 = emis + (size_t)w1 * NL + wv * 64 + g * 4;
        #pragma unroll
        for (int T = 0; T < 4; ++T) pfA[T] = *reinterpret_cast<const float4*>(e1 + T * 16);
    }
    __syncthreads();

#define CRF_STEP(t, RD, WR, pfC, pfN)                                           \
    {                                                                           \
        h8 bfr[8];                                                              \
        _Pragma("unroll")                                                       \
        for (int kt = 0; kt < 8; ++kt)                                          \
            bfr[kt] = *reinterpret_cast<const h8*>(&ea[RD][b][kt * 32 + g * 8]);\
        float4 pm4 = *reinterpret_cast<const float4*>(&pmaxp[RD][b][0]);        \
        float B2cur = fmaxf(fmaxf(pm4.x, pm4.y), fmaxf(pm4.z, pm4.w)) + SHIFT2; \
        if ((t) + 1 < NT) {                                                     \
            const int wn = wlds[b * NT + (t) + 1];                              \
            const float* ep = emis + (size_t)wn * NL + wv * 64 + g * 4;         \
            _Pragma("unroll")                                                   \
            for (int T = 0; T < 4; ++T)                                         \
                pfN[T] = *reinterpret_cast<const float4*>(ep + T * 16);         \
        }                                                                       \
        f32x4 acc[4] = { f32x4{0.f,0.f,0.f,0.f}, f32x4{0.f,0.f,0.f,0.f},        \
                         f32x4{0.f,0.f,0.f,0.f}, f32x4{0.f,0.f,0.f,0.f} };      \
        _Pragma("unroll")                                                       \
        for (int kt = 0; kt < 8; ++kt) {                                        \
            _Pragma("unroll")                                                   \
            for (int T = 0; T < 4; ++T)                                         \
                acc[T] = __builtin_amdgcn_mfma_f32_16x16x32_f16(                \
                             afr[T][kt], bfr[kt], acc[T], 0, 0, 0);             \
        }                                                                       \
        float al[4][4];                                                         \
        float vmax = -1e30f;                                                    \
        _Pragma("unroll")                                                       \
        for (int T = 0; T < 4; ++T) {                                           \
            al[T][0] = fmaf(pfC[T].x, INV_LN2, log2_fast(acc[T][0]) + B2prev);  \
            al[T][1] = fmaf(pfC[T].y, INV_LN2, log2_fast(acc[T][1]) + B2prev);  \
            al[T][2] = fmaf(pfC[T].z, INV_LN2, log2_fast(acc[T][2]) + B2prev);  \
            al[T][3] = fmaf(pfC[T].w, INV_LN2, log2_fast(acc[T][3]) + B2prev);  \
            vmax = fmaxf(vmax, fmaxf(fmaxf(al[T][0], al[T][1]),                 \
                                     fmaxf(al[T][2], al[T][3])));               \
        }                                                                       \
        vmax = fmaxf(vmax, __shfl_xor(vmax, 16));                               \
        vmax = fmaxf(vmax, __shfl_xor(vmax, 32));                               \
        if (g == 0) pmaxp[WR][b][wv] = vmax;                                    \
        _Pragma("unroll")                                                       \
        for (int T = 0; T < 4; ++T) {                                           \
            h4 q = { (_Float16)fminf(exp2_fast(al[T][0] - B2cur), 60000.f),     \
                     (_Float16)fminf(exp2_fast(al[T][1] - B2cur), 60000.f),     \
                     (_Float16)fminf(exp2_fast(al[T][2] - B2cur), 60000.f),     \
                     (_Float16)fminf(exp2_fast(al[T][3] - B2cur), 60000.f) };   \
            *reinterpret_cast<h4*>(&ea[WR][b][wv * 64 + T * 16 + g * 4]) = q;   \
        }                                                                       \
        B2prev = B2cur;                                                         \
        __syncthreads();                                                        \
    }

    for (int t = 1; t < NT; t += 2) {
        CRF_STEP(t, 0, 1, pfA, pfB);
        if (t + 1 < NT) CRF_STEP(t + 1, 1, 0, pfB, pfA);
    }
#undef CRF_STEP

    // ---- final: logZ_b = ln2 * (B2_last + log2(sum_i EA_last[i,b])) ----
    {
        const int part = tid & 15;
        const int bb   = tid >> 4;
        h8 v0 = *reinterpret_cast<const h8*>(&ea[1][bb][part * 16]);
        h8 v1 = *reinterpret_cast<const h8*>(&ea[1][bb][part * 16 + 8]);
        float s = 0.f;
        #pragma unroll
        for (int j = 0; j < 8; ++j) s += (float)v0[j] + (float)v1[j];
        sump[bb][part] = s;
    }
    __syncthreads();
    if (tid < BG) {
        float tot = 0.f;
        #pragma unroll
        for (int p = 0; p < 16; ++p) tot += sump[tid][p];
        // threads 0..15 have b == tid, so their B2prev is batch tid's base
        lzb[tid] = (B2prev + log2_fast(tot)) * LN2;
    }
    __syncthreads();
    if (tid == 0) {
        float p = 0.f;
        #pragma unroll
        for (int j = 0; j < BG; ++j) p += lzb[j];
        bout[blockIdx.x] = p;
    }
}

__global__ void crf_reduce(const float* __restrict__ bout, float* __restrict__ out)
{
    if (threadIdx.x == 0) {
        float s = 0.f;
        for (int j = 0; j < NWG; ++j) s += bout[j];
        out[0] = s;
    }
}

extern "C" void kernel_launch(void* const* d_in, const int* in_sizes, int n_in,
                              void* d_out, int out_size, void* d_ws, size_t ws_size,
                              hipStream_t stream)
{
    const float* emis  = (const float*)d_in[0];
    const float* trans = (const float*)d_in[1];
    const int*   words = (const int*)d_in[2];
    float* out  = (float*)d_out;
    float* bout = (float*)d_ws;   // NWG floats of scratch

    crf_forward<<<NWG, 256, 0, stream>>>(emis, trans, words, bout);
    crf_reduce<<<1, 64, 0, stream>>>(bout, out);
}

// Round 5
// 435.312 us; speedup vs baseline: 1.2314x; 1.2314x over previous
//
#include <hip/hip_runtime.h>

#define NB 128
#define NT 512
#define NL 256
#define BG 16            // batches per workgroup
#define NWG (NB / BG)    // 8 workgroups

typedef _Float16 h8 __attribute__((ext_vector_type(8)));
typedef _Float16 h4 __attribute__((ext_vector_type(4)));
typedef float f32x4 __attribute__((ext_vector_type(4)));

#define EAP 264                    // padded k-stride (f16), row = 528 B (16B-aligned)
#define SHIFT2 6.0f                // base-2 headroom shift
#define INV_LN2 1.4426950408889634f
#define LN2 0.6931471805599453f

__device__ inline float log2_fast(float x) {
#if __has_builtin(__builtin_amdgcn_logf)
    return __builtin_amdgcn_logf(x);      // v_log_f32 (base-2)
#else
    return __log2f(x);
#endif
}
__device__ inline float exp2_fast(float x) {
#if __has_builtin(__builtin_amdgcn_exp2f)
    return __builtin_amdgcn_exp2f(x);     // v_exp_f32 (base-2)
#else
    return exp2f(x);
#endif
}

// One WG (512 thr = 8 waves, 2 waves/SIMD) per 16 batches.
// Wave wv owns 32 output rows (2 i-tiles). Per step:
//   D(256x16) = expM(256x256, f16 A-frags in VGPRs) x EA(256x16, f16 LDS)
// then exact f32 log-space reconstruction (round-4 scheme, verified absmax 0):
//   alpha2[i,b] = e_t[i,b]*INV_LN2 + log2(D[i,b]) + B2_prev(b)
//   EA_next     = 2^(alpha2 - B2_cur),  B2_cur = (stale exact max) + SHIFT2
// Latency fixes vs round 4: 2 waves/SIMD, MFMA chains split 8->4+4,
// emis gather prefetched 2 steps ahead, word index 4 steps ahead (no wlds).
__global__ __launch_bounds__(512, 2) void crf_forward(
    const float* __restrict__ emis,
    const float* __restrict__ trans,
    const int*   __restrict__ words,
    float*       __restrict__ bout)
{
    const int tid = threadIdx.x;
    const int l   = tid & 63;
    const int wv  = tid >> 6;    // 0..7
    const int g   = l >> 4;      // 0..3
    const int b   = l & 15;

    __shared__ _Float16 ea[2][BG][EAP];              // 2^(alpha2 - B2), dbuf
    __shared__ __align__(16) float pmaxp[2][BG][8];  // per-wave partial maxes
    __shared__ float sump[BG][16];
    __shared__ float lzb[BG];

    const int wrow = (blockIdx.x * BG + b) * NT;

    // ---- A-fragments: exp(trans) rows owned by this wave (64 VGPRs) ----
    h8 afr[2][8];
    #pragma unroll
    for (int T = 0; T < 2; ++T) {
        const int row = wv * 32 + T * 16 + b;
        #pragma unroll
        for (int kt = 0; kt < 8; ++kt) {
            const float* src = trans + row * NL + kt * 32 + g * 8;
            float4 v0 = *reinterpret_cast<const float4*>(src);
            float4 v1 = *reinterpret_cast<const float4*>(src + 4);
            h8 a;
            a[0] = (_Float16)__expf(v0.x); a[1] = (_Float16)__expf(v0.y);
            a[2] = (_Float16)__expf(v0.z); a[3] = (_Float16)__expf(v0.w);
            a[4] = (_Float16)__expf(v1.x); a[5] = (_Float16)__expf(v1.y);
            a[6] = (_Float16)__expf(v1.z); a[7] = (_Float16)__expf(v1.w);
            afr[T][kt] = a;
        }
    }

    // ---- word-index pipeline (4 ahead) + emission pipeline (2 ahead) ----
    const int w0 = words[wrow + 0];
    const int w1 = words[wrow + 1];
    const int w2 = words[wrow + 2];
    int wregA = words[wrow + 3];   // used at t=1 to prefetch e[3]
    int wregB = words[wrow + 4];   // used at t=2 to prefetch e[4]

    // ---- t=0: alpha2_0 = e0*INV_LN2 ; EA_0 = 2^alpha2_0 (B2_0 = 0) ----
    float B2prev = 0.f;
    {
        const float* e0 = emis + (size_t)w0 * NL + wv * 32 + g * 4;
        float vmax = -1e30f;
        #pragma unroll
        for (int T = 0; T < 2; ++T) {
            float4 v = *reinterpret_cast<const float4*>(e0 + T * 16);
            float a0 = v.x * INV_LN2, a1 = v.y * INV_LN2;
            float a2 = v.z * INV_LN2, a3 = v.w * INV_LN2;
            vmax = fmaxf(fmaxf(vmax, fmaxf(a0, a1)), fmaxf(a2, a3));
            h4 q = { (_Float16)exp2_fast(a0), (_Float16)exp2_fast(a1),
                     (_Float16)exp2_fast(a2), (_Float16)exp2_fast(a3) };
            *reinterpret_cast<h4*>(&ea[0][b][wv * 32 + T * 16 + g * 4]) = q;
        }
        vmax = fmaxf(vmax, __shfl_xor(vmax, 16));
        vmax = fmaxf(vmax, __shfl_xor(vmax, 32));
        if (g == 0) pmaxp[0][b][wv] = vmax;
    }
    float4 pfA[2], pfB[2];
    {
        const float* p1 = emis + (size_t)w1 * NL + wv * 32 + g * 4;
        pfA[0] = *reinterpret_cast<const float4*>(p1);
        pfA[1] = *reinterpret_cast<const float4*>(p1 + 16);
        const float* p2 = emis + (size_t)w2 * NL + wv * 32 + g * 4;
        pfB[0] = *reinterpret_cast<const float4*>(p2);
        pfB[1] = *reinterpret_cast<const float4*>(p2 + 16);
    }
    __syncthreads();

#define CRF_STEP(t, RD, WR, PF, WREG)                                           \
    {                                                                           \
        h8 bfr[8];                                                              \
        _Pragma("unroll")                                                       \
        for (int kt = 0; kt < 8; ++kt)                                          \
            bfr[kt] = *reinterpret_cast<const h8*>(&ea[RD][b][kt * 32 + g * 8]);\
        float4 pm0 = *reinterpret_cast<const float4*>(&pmaxp[RD][b][0]);        \
        float4 pm1 = *reinterpret_cast<const float4*>(&pmaxp[RD][b][4]);        \
        float B2cur = fmaxf(fmaxf(fmaxf(pm0.x, pm0.y), fmaxf(pm0.z, pm0.w)),    \
                            fmaxf(fmaxf(pm1.x, pm1.y), fmaxf(pm1.z, pm1.w)))    \
                      + SHIFT2;                                                 \
        float4 eC0 = PF[0], eC1 = PF[1];                                        \
        if ((t) + 2 < NT) {                                                     \
            const float* ep = emis + (size_t)WREG * NL + wv * 32 + g * 4;       \
            PF[0] = *reinterpret_cast<const float4*>(ep);                       \
            PF[1] = *reinterpret_cast<const float4*>(ep + 16);                  \
        }                                                                       \
        if ((t) + 4 < NT) WREG = words[wrow + (t) + 4];                         \
        f32x4 accA[2] = { f32x4{0.f,0.f,0.f,0.f}, f32x4{0.f,0.f,0.f,0.f} };     \
        f32x4 accB[2] = { f32x4{0.f,0.f,0.f,0.f}, f32x4{0.f,0.f,0.f,0.f} };     \
        _Pragma("unroll")                                                       \
        for (int kt = 0; kt < 4; ++kt) {                                        \
            accA[0] = __builtin_amdgcn_mfma_f32_16x16x32_f16(                   \
                          afr[0][kt], bfr[kt], accA[0], 0, 0, 0);               \
            accA[1] = __builtin_amdgcn_mfma_f32_16x16x32_f16(                   \
                          afr[1][kt], bfr[kt], accA[1], 0, 0, 0);               \
            accB[0] = __builtin_amdgcn_mfma_f32_16x16x32_f16(                   \
                          afr[0][kt + 4], bfr[kt + 4], accB[0], 0, 0, 0);       \
            accB[1] = __builtin_amdgcn_mfma_f32_16x16x32_f16(                   \
                          afr[1][kt + 4], bfr[kt + 4], accB[1], 0, 0, 0);       \
        }                                                                       \
        f32x4 acc0 = accA[0] + accB[0];                                         \
        f32x4 acc1 = accA[1] + accB[1];                                         \
        float al[2][4];                                                         \
        float vmax = -1e30f;                                                    \
        al[0][0] = fmaf(eC0.x, INV_LN2, log2_fast(acc0[0]) + B2prev);           \
        al[0][1] = fmaf(eC0.y, INV_LN2, log2_fast(acc0[1]) + B2prev);           \
        al[0][2] = fmaf(eC0.z, INV_LN2, log2_fast(acc0[2]) + B2prev);           \
        al[0][3] = fmaf(eC0.w, INV_LN2, log2_fast(acc0[3]) + B2prev);           \
        al[1][0] = fmaf(eC1.x, INV_LN2, log2_fast(acc1[0]) + B2prev);           \
        al[1][1] = fmaf(eC1.y, INV_LN2, log2_fast(acc1[1]) + B2prev);           \
        al[1][2] = fmaf(eC1.z, INV_LN2, log2_fast(acc1[2]) + B2prev);           \
        al[1][3] = fmaf(eC1.w, INV_LN2, log2_fast(acc1[3]) + B2prev);           \
        vmax = fmaxf(fmaxf(fmaxf(al[0][0], al[0][1]), fmaxf(al[0][2], al[0][3])),\
                     fmaxf(fmaxf(al[1][0], al[1][1]), fmaxf(al[1][2], al[1][3])));\
        vmax = fmaxf(vmax, __shfl_xor(vmax, 16));                               \
        vmax = fmaxf(vmax, __shfl_xor(vmax, 32));                               \
        if (g == 0) pmaxp[WR][b][wv] = vmax;                                    \
        _Pragma("unroll")                                                       \
        for (int T = 0; T < 2; ++T) {                                           \
            h4 q = { (_Float16)fminf(exp2_fast(al[T][0] - B2cur), 60000.f),     \
                     (_Float16)fminf(exp2_fast(al[T][1] - B2cur), 60000.f),     \
                     (_Float16)fminf(exp2_fast(al[T][2] - B2cur), 60000.f),     \
                     (_Float16)fminf(exp2_fast(al[T][3] - B2cur), 60000.f) };   \
            *reinterpret_cast<h4*>(&ea[WR][b][wv * 32 + T * 16 + g * 4]) = q;   \
        }                                                                       \
        B2prev = B2cur;                                                         \
        __syncthreads();                                                        \
    }

    for (int t = 1; t < NT; t += 2) {
        CRF_STEP(t, 0, 1, pfA, wregA);
        if (t + 1 < NT) CRF_STEP(t + 1, 1, 0, pfB, wregB);
    }
#undef CRF_STEP

    // ---- final (NT-1 odd -> last EA in buffer 1):
    //      logZ_b = ln2 * (B2_last + log2(sum_i EA_last[i,b])) ----
    if (tid < 256) {
        const int part = tid & 15;
        const int bb   = tid >> 4;
        h8 v0 = *reinterpret_cast<const h8*>(&ea[1][bb][part * 16]);
        h8 v1 = *reinterpret_cast<const h8*>(&ea[1][bb][part * 16 + 8]);
        float s = 0.f;
        #pragma unroll
        for (int j = 0; j < 8; ++j) s += (float)v0[j] + (float)v1[j];
        sump[bb][part] = s;
    }
    __syncthreads();
    if (tid < BG) {
        float tot = 0.f;
        #pragma unroll
        for (int p = 0; p < 16; ++p) tot += sump[tid][p];
        // threads 0..15 have b == tid, so their B2prev is batch tid's base
        lzb[tid] = (B2prev + log2_fast(tot)) * LN2;
    }
    __syncthreads();
    if (tid == 0) {
        float p = 0.f;
        #pragma unroll
        for (int j = 0; j < BG; ++j) p += lzb[j];
        bout[blockIdx.x] = p;
    }
}

__global__ void crf_reduce(const float* __restrict__ bout, float* __restrict__ out)
{
    if (threadIdx.x == 0) {
        float s = 0.f;
        for (int j = 0; j < NWG; ++j) s += bout[j];
        out[0] = s;
    }
}

extern "C" void kernel_launch(void* const* d_in, const int* in_sizes, int n_in,
                              void* d_out, int out_size, void* d_ws, size_t ws_size,
                              hipStream_t stream)
{
    const float* emis  = (const float*)d_in[0];
    const float* trans = (const float*)d_in[1];
    const int*   words = (const int*)d_in[2];
    float* out  = (float*)d_out;
    float* bout = (float*)d_ws;   // NWG floats of scratch

    crf_forward<<<NWG, 512, 0, stream>>>(emis, trans, words, bout);
    crf_reduce<<<1, 64, 0, stream>>>(bout, out);
}

// Round 6
// 429.637 us; speedup vs baseline: 1.2477x; 1.0132x over previous
//
#include <hip/hip_runtime.h>

#define NB 128
#define NT 512
#define NL 256
#define BG 16            // batches per workgroup
#define NWG (NB / BG)    // 8 workgroups

typedef float f32x4 __attribute__((ext_vector_type(4)));

#define EASTRIDE 264     // bytes per batch row of EA (256 + 8 pad, 8B-aligned)
#define PMSTRIDE 36      // floats per batch row of pmax partials (32 + 4 pad)
#define SHIFT2 4.0f      // base-2 headroom shift (EA max ~2^5.4, spikes < 448)
#define INV_LN2 1.4426950408889634f
#define LN2 0.6931471805599453f

__device__ inline float log2_fast(float x) {
#if __has_builtin(__builtin_amdgcn_logf)
    return __builtin_amdgcn_logf(x);
#else
    return __log2f(x);
#endif
}
__device__ inline float exp2_fast(float x) {
#if __has_builtin(__builtin_amdgcn_exp2f)
    return __builtin_amdgcn_exp2f(x);
#else
    return exp2f(x);
#endif
}

// Barrier that waits only on LDS ops (lgkmcnt) — emission prefetch global
// loads stay in flight across it (counted-vmcnt pattern, T4).
__device__ inline void barrier_lds_only() {
    asm volatile("s_waitcnt lgkmcnt(0)" ::: "memory");
    __builtin_amdgcn_s_barrier();
    asm volatile("" ::: "memory");
}

// pack 4 f32 -> 4 fp8 e4m3 bytes (one u32)
__device__ inline unsigned pk_fp8x4(float a, float b, float c, float d) {
    int w = __builtin_amdgcn_cvt_pk_fp8_f32(a, b, 0, false);
    w     = __builtin_amdgcn_cvt_pk_fp8_f32(c, d, w, true);
    return (unsigned)w;
}

__device__ inline float4 max4(float4 a, float4 b) {
    return make_float4(fmaxf(a.x, b.x), fmaxf(a.y, b.y),
                       fmaxf(a.z, b.z), fmaxf(a.w, b.w));
}

// One WG (512 thr = 8 waves) per 16 batches.
//   D(256x16) = expM(256x256, fp8 A-frags in VGPRs) x EA(256x16, fp8 LDS)
// via mfma_f32_16x16x32_fp8_fp8 (2 i-tiles x 8 k-tiles per wave), then exact
// f32 log-space reconstruction (round-4/5 scheme, verified):
//   alpha2[i,b] = e_t[i,b]*INV_LN2 + log2(D[i,b]) + B2_prev(b)
//   EA_next     = 2^(alpha2 - B2_cur),  B2_cur = (stale exact max) + SHIFT2
// Lane mapping (16x16x32, dtype-independent): b = l&15, g = l>>4;
// A: row=b, k=g*8+j (byte j); B: col=b, k=g*8+j; D: col=b, row=g*4+reg.
__global__ __launch_bounds__(512, 2) void crf_forward(
    const float* __restrict__ emis,
    const float* __restrict__ trans,
    const int*   __restrict__ words,
    float*       __restrict__ bout)
{
    const int tid = threadIdx.x;
    const int l   = tid & 63;
    const int wv  = tid >> 6;    // 0..7
    const int g   = l >> 4;      // 0..3
    const int b   = l & 15;

    __shared__ __align__(16) unsigned char ea[2][BG][EASTRIDE]; // fp8 EA, dbuf
    __shared__ __align__(16) float pmaxp[2][BG][PMSTRIDE];      // per-(wv,g) maxes
    __shared__ float sump[BG][16];
    __shared__ float lzb[BG];

    const int wrow = (blockIdx.x * BG + b) * NT;

    // ---- A-fragments: exp(trans) rows owned by this wave, fp8 (32 VGPRs) ----
    long afr[2][8];
    #pragma unroll
    for (int T = 0; T < 2; ++T) {
        const int row = wv * 32 + T * 16 + b;
        #pragma unroll
        for (int kt = 0; kt < 8; ++kt) {
            const float* src = trans + row * NL + kt * 32 + g * 8;
            float4 v0 = *reinterpret_cast<const float4*>(src);
            float4 v1 = *reinterpret_cast<const float4*>(src + 4);
            unsigned w0 = pk_fp8x4(__expf(v0.x), __expf(v0.y), __expf(v0.z), __expf(v0.w));
            unsigned w1 = pk_fp8x4(__expf(v1.x), __expf(v1.y), __expf(v1.z), __expf(v1.w));
            afr[T][kt] = (long)(((unsigned long long)w1 << 32) | w0);
        }
    }

    // ---- word-index pipeline (4 ahead) + emission pipeline (2 ahead) ----
    const int w0 = words[wrow + 0];
    const int w1 = words[wrow + 1];
    const int w2 = words[wrow + 2];
    int wregA = words[wrow + 3];
    int wregB = words[wrow + 4];

    // ---- t=0: alpha2_0 = e0*INV_LN2 ; EA_0 = 2^alpha2_0 (B2_0 = 0) ----
    float B2prev = 0.f;
    {
        const float* e0 = emis + (size_t)w0 * NL + wv * 32 + g * 4;
        float vmax = -1e30f;
        #pragma unroll
        for (int T = 0; T < 2; ++T) {
            float4 v = *reinterpret_cast<const float4*>(e0 + T * 16);
            float a0 = v.x * INV_LN2, a1 = v.y * INV_LN2;
            float a2 = v.z * INV_LN2, a3 = v.w * INV_LN2;
            vmax = fmaxf(fmaxf(vmax, fmaxf(a0, a1)), fmaxf(a2, a3));
            unsigned q = pk_fp8x4(fminf(exp2_fast(a0), 440.f),
                                  fminf(exp2_fast(a1), 440.f),
                                  fminf(exp2_fast(a2), 440.f),
                                  fminf(exp2_fast(a3), 440.f));
            *reinterpret_cast<unsigned*>(&ea[0][b][wv * 32 + T * 16 + g * 4]) = q;
        }
        pmaxp[0][b][wv * 4 + g] = vmax;
    }
    float4 pfA[2], pfB[2];
    {
        const float* p1 = emis + (size_t)w1 * NL + wv * 32 + g * 4;
        pfA[0] = *reinterpret_cast<const float4*>(p1);
        pfA[1] = *reinterpret_cast<const float4*>(p1 + 16);
        const float* p2 = emis + (size_t)w2 * NL + wv * 32 + g * 4;
        pfB[0] = *reinterpret_cast<const float4*>(p2);
        pfB[1] = *reinterpret_cast<const float4*>(p2 + 16);
    }
    barrier_lds_only();

#define CRF_STEP(t, RD, WR, PF, WREG)                                           \
    {                                                                           \
        long bfr[8];                                                            \
        _Pragma("unroll")                                                       \
        for (int kt = 0; kt < 8; ++kt)                                          \
            bfr[kt] = *reinterpret_cast<const long*>(&ea[RD][b][kt * 32 + g * 8]);\
        /* stale exact max over 32 partials (broadcast reads, slack-rich) */    \
        const float4* pmr = reinterpret_cast<const float4*>(&pmaxp[RD][b][0]);  \
        float4 m01 = max4(pmr[0], pmr[1]);                                      \
        float4 m23 = max4(pmr[2], pmr[3]);                                      \
        float4 m45 = max4(pmr[4], pmr[5]);                                      \
        float4 m67 = max4(pmr[6], pmr[7]);                                      \
        float4 mm  = max4(max4(m01, m23), max4(m45, m67));                      \
        float B2cur = fmaxf(fmaxf(mm.x, mm.y), fmaxf(mm.z, mm.w)) + SHIFT2;     \
        float4 eC0 = PF[0], eC1 = PF[1];                                        \
        if ((t) + 2 < NT) {                                                     \
            const float* ep = emis + (size_t)WREG * NL + wv * 32 + g * 4;       \
            PF[0] = *reinterpret_cast<const float4*>(ep);                       \
            PF[1] = *reinterpret_cast<const float4*>(ep + 16);                  \
        }                                                                       \
        if ((t) + 4 < NT) WREG = words[wrow + (t) + 4];                         \
        f32x4 accA0 = {0.f,0.f,0.f,0.f}, accA1 = {0.f,0.f,0.f,0.f};             \
        f32x4 accB0 = {0.f,0.f,0.f,0.f}, accB1 = {0.f,0.f,0.f,0.f};             \
        _Pragma("unroll")                                                       \
        for (int kt = 0; kt < 4; ++kt) {                                        \
            accA0 = __builtin_amdgcn_mfma_f32_16x16x32_fp8_fp8(                 \
                        afr[0][kt], bfr[kt], accA0, 0, 0, 0);                   \
            accA1 = __builtin_amdgcn_mfma_f32_16x16x32_fp8_fp8(                 \
                        afr[1][kt], bfr[kt], accA1, 0, 0, 0);                   \
            accB0 = __builtin_amdgcn_mfma_f32_16x16x32_fp8_fp8(                 \
                        afr[0][kt + 4], bfr[kt + 4], accB0, 0, 0, 0);           \
            accB1 = __builtin_amdgcn_mfma_f32_16x16x32_fp8_fp8(                 \
                        afr[1][kt + 4], bfr[kt + 4], accB1, 0, 0, 0);           \
        }                                                                       \
        f32x4 acc0 = accA0 + accB0;                                             \
        f32x4 acc1 = accA1 + accB1;                                             \
        float al0[4], al1[4];                                                   \
        al0[0] = fmaf(eC0.x, INV_LN2, log2_fast(acc0[0]) + B2prev);             \
        al0[1] = fmaf(eC0.y, INV_LN2, log2_fast(acc0[1]) + B2prev);             \
        al0[2] = fmaf(eC0.z, INV_LN2, log2_fast(acc0[2]) + B2prev);             \
        al0[3] = fmaf(eC0.w, INV_LN2, log2_fast(acc0[3]) + B2prev);             \
        al1[0] = fmaf(eC1.x, INV_LN2, log2_fast(acc1[0]) + B2prev);             \
        al1[1] = fmaf(eC1.y, INV_LN2, log2_fast(acc1[1]) + B2prev);             \
        al1[2] = fmaf(eC1.z, INV_LN2, log2_fast(acc1[2]) + B2prev);             \
        al1[3] = fmaf(eC1.w, INV_LN2, log2_fast(acc1[3]) + B2prev);             \
        float vmax = fmaxf(fmaxf(fmaxf(al0[0], al0[1]), fmaxf(al0[2], al0[3])), \
                           fmaxf(fmaxf(al1[0], al1[1]), fmaxf(al1[2], al1[3])));\
        pmaxp[WR][b][wv * 4 + g] = vmax;   /* no shuffles on barrier path */    \
        {                                                                       \
            unsigned q0 = pk_fp8x4(fminf(exp2_fast(al0[0] - B2cur), 440.f),     \
                                   fminf(exp2_fast(al0[1] - B2cur), 440.f),     \
                                   fminf(exp2_fast(al0[2] - B2cur), 440.f),     \
                                   fminf(exp2_fast(al0[3] - B2cur), 440.f));    \
            unsigned q1 = pk_fp8x4(fminf(exp2_fast(al1[0] - B2cur), 440.f),     \
                                   fminf(exp2_fast(al1[1] - B2cur), 440.f),     \
                                   fminf(exp2_fast(al1[2] - B2cur), 440.f),     \
                                   fminf(exp2_fast(al1[3] - B2cur), 440.f));    \
            *reinterpret_cast<unsigned*>(&ea[WR][b][wv * 32 + g * 4])      = q0;\
            *reinterpret_cast<unsigned*>(&ea[WR][b][wv * 32 + 16 + g * 4]) = q1;\
        }                                                                       \
        B2prev = B2cur;                                                         \
        barrier_lds_only();                                                     \
    }

    for (int t = 1; t < NT; t += 2) {
        CRF_STEP(t, 0, 1, pfA, wregA);
        if (t + 1 < NT) CRF_STEP(t + 1, 1, 0, pfB, wregB);
    }
#undef CRF_STEP

    // ---- final (last EA in buffer 1):
    //      logZ_b = ln2 * (B2_last + log2(sum_i EA_last[i,b])) ----
    if (tid < 256) {
        const int part = tid & 15;
        const int bb   = tid >> 4;
        const unsigned* p = reinterpret_cast<const unsigned*>(&ea[1][bb][part * 16]);
        float s = 0.f;
        #pragma unroll
        for (int w = 0; w < 4; ++w) {
            unsigned u = p[w];
            s += __builtin_amdgcn_cvt_f32_fp8((int)u, 0);
            s += __builtin_amdgcn_cvt_f32_fp8((int)u, 1);
            s += __builtin_amdgcn_cvt_f32_fp8((int)u, 2);
            s += __builtin_amdgcn_cvt_f32_fp8((int)u, 3);
        }
        sump[bb][part] = s;
    }
    __syncthreads();
    if (tid < BG) {
        float tot = 0.f;
        #pragma unroll
        for (int p = 0; p < 16; ++p) tot += sump[tid][p];
        // threads 0..15 have b == tid, so their B2prev is batch tid's base
        lzb[tid] = (B2prev + log2_fast(tot)) * LN2;
    }
    __syncthreads();
    if (tid == 0) {
        float p = 0.f;
        #pragma unroll
        for (int j = 0; j < BG; ++j) p += lzb[j];
        bout[blockIdx.x] = p;
    }
}

__global__ void crf_reduce(const float* __restrict__ bout, float* __restrict__ out)
{
    if (threadIdx.x == 0) {
        float s = 0.f;
        for (int j = 0; j < NWG; ++j) s += bout[j];
        out[0] = s;
    }
}

extern "C" void kernel_launch(void* const* d_in, const int* in_sizes, int n_in,
                              void* d_out, int out_size, void* d_ws, size_t ws_size,
                              hipStream_t stream)
{
    const float* emis  = (const float*)d_in[0];
    const float* trans = (const float*)d_in[1];
    const int*   words = (const int*)d_in[2];
    float* out  = (float*)d_out;
    float* bout = (float*)d_ws;   // NWG floats of scratch

    crf_forward<<<NWG, 512, 0, stream>>>(emis, trans, words, bout);
    crf_reduce<<<1, 64, 0, stream>>>(bout, out);
}

// Round 7
// 413.932 us; speedup vs baseline: 1.2950x; 1.0379x over previous
//
#include <hip/hip_runtime.h>

#define NB 128
#define NT 512
#define NL 256
#define BG 16            // batches per workgroup
#define NWG (NB / BG)    // 8 workgroups

typedef float f32x4 __attribute__((ext_vector_type(4)));

#define EASTRIDE 264     // bytes per batch row of EA (256 + 8 pad)
#define INV_LN2 1.4426950408889634f
#define LN2 0.6931471805599453f

__device__ inline float log2_fast(float x) {
#if __has_builtin(__builtin_amdgcn_logf)
    return __builtin_amdgcn_logf(x);
#else
    return __log2f(x);
#endif
}
__device__ inline float exp2_fast(float x) {
#if __has_builtin(__builtin_amdgcn_exp2f)
    return __builtin_amdgcn_exp2f(x);
#else
    return exp2f(x);
#endif
}

// Barrier that waits only on LDS ops — emission prefetch global loads stay
// in flight across it (counted-vmcnt pattern, T4).
__device__ inline void barrier_lds_only() {
    asm volatile("s_waitcnt lgkmcnt(0)" ::: "memory");
    __builtin_amdgcn_s_barrier();
    asm volatile("" ::: "memory");
}

// pack 4 f32 -> 4 fp8 e4m3 bytes (saturating)
__device__ inline unsigned pk_fp8x4(float a, float b, float c, float d) {
    int w = __builtin_amdgcn_cvt_pk_fp8_f32(a, b, 0, false);
    w     = __builtin_amdgcn_cvt_pk_fp8_f32(c, d, w, true);
    return (unsigned)w;
}

// One WG (512 thr = 8 waves) per 16 batches.
// Exp-space recurrence with EXACT power-of-2 normalization (no per-element
// log/exp in the steady loop):
//   v[i,b]   = (sum_k expM[i,k] * EA[k,b]) * exp2(e_t[i,b]*INV_LN2)
//   k_b      = exponent(max_i v[i,b])        (exact current max, 2 barriers)
//   EA_next  = v * 2^-k_b   (max in [1,2), fp8 e4m3)
//   S_b     += k_b                            (exact integer accumulation)
// logZ_b = ln2 * (S_b + log2(sum_i EA_last)).  Stability: normalization is an
// exact representation change (integer exponents), no float scale feedback.
// Lane mapping (16x16x32, dtype-independent): b = l&15, g = l>>4;
// A: row=b, k=g*8+j; B: col=b, k=g*8+j; D: col=b, row=g*4+reg.
__global__ __launch_bounds__(512, 2) void crf_forward(
    const float* __restrict__ emis,
    const float* __restrict__ trans,
    const int*   __restrict__ words,
    float*       __restrict__ bout)
{
    const int tid = threadIdx.x;
    const int l   = tid & 63;
    const int wv  = tid >> 6;    // 0..7
    const int g   = l >> 4;      // 0..3
    const int b   = l & 15;

    __shared__ __align__(16) unsigned char ea[2][BG][EASTRIDE]; // fp8 EA, dbuf
    __shared__ __align__(16) float pm[BG][8];   // per-(batch,wave) partial max
    __shared__ float sump[BG][16];
    __shared__ float lzb[BG];

    const int wrow = (blockIdx.x * BG + b) * NT;

    // ---- A-fragments: exp(trans) rows owned by this wave, fp8 (32 VGPRs) ----
    long afr[2][8];
    #pragma unroll
    for (int T = 0; T < 2; ++T) {
        const int row = wv * 32 + T * 16 + b;
        #pragma unroll
        for (int kt = 0; kt < 8; ++kt) {
            const float* src = trans + row * NL + kt * 32 + g * 8;
            float4 v0 = *reinterpret_cast<const float4*>(src);
            float4 v1 = *reinterpret_cast<const float4*>(src + 4);
            unsigned u0 = pk_fp8x4(__expf(v0.x), __expf(v0.y), __expf(v0.z), __expf(v0.w));
            unsigned u1 = pk_fp8x4(__expf(v1.x), __expf(v1.y), __expf(v1.z), __expf(v1.w));
            afr[T][kt] = (long)(((unsigned long long)u1 << 32) | u0);
        }
    }

    // ---- word-index pipeline (4 ahead) + emission pipeline (2 ahead) ----
    const int w0 = words[wrow + 0];
    const int w1 = words[wrow + 1];
    const int w2 = words[wrow + 2];
    int wregA = words[wrow + 3];
    int wregB = words[wrow + 4];

    float S = 0.f;   // per-batch exponent accumulator (exact small ints)

    // ---- t=0 : v = 2^(e0*INV_LN2), then normalize ----
    {
        const float* e0 = emis + (size_t)w0 * NL + wv * 32 + g * 4;
        float4 va = *reinterpret_cast<const float4*>(e0);
        float4 vb = *reinterpret_cast<const float4*>(e0 + 16);
        float v0[4] = { exp2_fast(va.x * INV_LN2), exp2_fast(va.y * INV_LN2),
                        exp2_fast(va.z * INV_LN2), exp2_fast(va.w * INV_LN2) };
        float v1[4] = { exp2_fast(vb.x * INV_LN2), exp2_fast(vb.y * INV_LN2),
                        exp2_fast(vb.z * INV_LN2), exp2_fast(vb.w * INV_LN2) };
        float m = fmaxf(fmaxf(fmaxf(v0[0], v0[1]), fmaxf(v0[2], v0[3])),
                        fmaxf(fmaxf(v1[0], v1[1]), fmaxf(v1[2], v1[3])));
        m = fmaxf(m, __shfl_xor(m, 16));
        m = fmaxf(m, __shfl_xor(m, 32));
        if (g == 0) pm[b][wv] = m;
        barrier_lds_only();
        float4 q0 = *reinterpret_cast<const float4*>(&pm[b][0]);
        float4 q1 = *reinterpret_cast<const float4*>(&pm[b][4]);
        float gm = fmaxf(fmaxf(fmaxf(q0.x, q0.y), fmaxf(q0.z, q0.w)),
                         fmaxf(fmaxf(q1.x, q1.y), fmaxf(q1.z, q1.w)));
        int kb = (int)(__builtin_bit_cast(unsigned, gm) >> 23) - 127;
        S += (float)kb;
        float sc = __builtin_bit_cast(float, (unsigned)(127 - kb) << 23);
        *reinterpret_cast<unsigned*>(&ea[0][b][wv * 32 + g * 4]) =
            pk_fp8x4(v0[0] * sc, v0[1] * sc, v0[2] * sc, v0[3] * sc);
        *reinterpret_cast<unsigned*>(&ea[0][b][wv * 32 + 16 + g * 4]) =
            pk_fp8x4(v1[0] * sc, v1[1] * sc, v1[2] * sc, v1[3] * sc);
    }
    float4 pfA[2], pfB[2];
    {
        const float* p1 = emis + (size_t)w1 * NL + wv * 32 + g * 4;
        pfA[0] = *reinterpret_cast<const float4*>(p1);
        pfA[1] = *reinterpret_cast<const float4*>(p1 + 16);
        const float* p2 = emis + (size_t)w2 * NL + wv * 32 + g * 4;
        pfB[0] = *reinterpret_cast<const float4*>(p2);
        pfB[1] = *reinterpret_cast<const float4*>(p2 + 16);
    }
    barrier_lds_only();

#define CRF_STEP(t, RD, WR, PF, WREG)                                           \
    {                                                                           \
        long bfr[8];                                                            \
        _Pragma("unroll")                                                       \
        for (int kt = 0; kt < 8; ++kt)                                          \
            bfr[kt] = *reinterpret_cast<const long*>(&ea[RD][b][kt * 32 + g * 8]);\
        float4 eC0 = PF[0], eC1 = PF[1];                                        \
        if ((t) + 2 < NT) {                                                     \
            const float* ep = emis + (size_t)WREG * NL + wv * 32 + g * 4;       \
            PF[0] = *reinterpret_cast<const float4*>(ep);                       \
            PF[1] = *reinterpret_cast<const float4*>(ep + 16);                  \
        }                                                                       \
        if ((t) + 4 < NT) WREG = words[wrow + (t) + 4];                         \
        /* expE: depends only on prefetched regs -> hoists under MFMA wait */   \
        float ex0[4] = { exp2_fast(eC0.x * INV_LN2), exp2_fast(eC0.y * INV_LN2),\
                         exp2_fast(eC0.z * INV_LN2), exp2_fast(eC0.w * INV_LN2)};\
        float ex1[4] = { exp2_fast(eC1.x * INV_LN2), exp2_fast(eC1.y * INV_LN2),\
                         exp2_fast(eC1.z * INV_LN2), exp2_fast(eC1.w * INV_LN2)};\
        f32x4 accA0 = {0.f,0.f,0.f,0.f}, accA1 = {0.f,0.f,0.f,0.f};             \
        f32x4 accB0 = {0.f,0.f,0.f,0.f}, accB1 = {0.f,0.f,0.f,0.f};             \
        _Pragma("unroll")                                                       \
        for (int kt = 0; kt < 4; ++kt) {                                        \
            accA0 = __builtin_amdgcn_mfma_f32_16x16x32_fp8_fp8(                 \
                        afr[0][kt], bfr[kt], accA0, 0, 0, 0);                   \
            accA1 = __builtin_amdgcn_mfma_f32_16x16x32_fp8_fp8(                 \
                        afr[1][kt], bfr[kt], accA1, 0, 0, 0);                   \
            accB0 = __builtin_amdgcn_mfma_f32_16x16x32_fp8_fp8(                 \
                        afr[0][kt + 4], bfr[kt + 4], accB0, 0, 0, 0);           \
            accB1 = __builtin_amdgcn_mfma_f32_16x16x32_fp8_fp8(                 \
                        afr[1][kt + 4], bfr[kt + 4], accB1, 0, 0, 0);           \
        }                                                                       \
        float v0[4], v1[4];                                                     \
        v0[0] = (accA0[0] + accB0[0]) * ex0[0];                                 \
        v0[1] = (accA0[1] + accB0[1]) * ex0[1];                                 \
        v0[2] = (accA0[2] + accB0[2]) * ex0[2];                                 \
        v0[3] = (accA0[3] + accB0[3]) * ex0[3];                                 \
        v1[0] = (accA1[0] + accB1[0]) * ex1[0];                                 \
        v1[1] = (accA1[1] + accB1[1]) * ex1[1];                                 \
        v1[2] = (accA1[2] + accB1[2]) * ex1[2];                                 \
        v1[3] = (accA1[3] + accB1[3]) * ex1[3];                                 \
        float m = fmaxf(fmaxf(fmaxf(v0[0], v0[1]), fmaxf(v0[2], v0[3])),        \
                        fmaxf(fmaxf(v1[0], v1[1]), fmaxf(v1[2], v1[3])));       \
        m = fmaxf(m, __shfl_xor(m, 16));                                        \
        m = fmaxf(m, __shfl_xor(m, 32));                                        \
        if (g == 0) pm[b][wv] = m;                                              \
        barrier_lds_only();                                                     \
        float4 q0 = *reinterpret_cast<const float4*>(&pm[b][0]);                \
        float4 q1 = *reinterpret_cast<const float4*>(&pm[b][4]);                \
        float gm = fmaxf(fmaxf(fmaxf(q0.x, q0.y), fmaxf(q0.z, q0.w)),           \
                         fmaxf(fmaxf(q1.x, q1.y), fmaxf(q1.z, q1.w)));          \
        int kb = (int)(__builtin_bit_cast(unsigned, gm) >> 23) - 127;           \
        S += (float)kb;                                                         \
        float sc = __builtin_bit_cast(float, (unsigned)(127 - kb) << 23);       \
        *reinterpret_cast<unsigned*>(&ea[WR][b][wv * 32 + g * 4]) =             \
            pk_fp8x4(v0[0] * sc, v0[1] * sc, v0[2] * sc, v0[3] * sc);           \
        *reinterpret_cast<unsigned*>(&ea[WR][b][wv * 32 + 16 + g * 4]) =        \
            pk_fp8x4(v1[0] * sc, v1[1] * sc, v1[2] * sc, v1[3] * sc);           \
        barrier_lds_only();                                                     \
    }

    for (int t = 1; t < NT; t += 2) {
        CRF_STEP(t, 0, 1, pfA, wregA);
        if (t + 1 < NT) CRF_STEP(t + 1, 1, 0, pfB, wregB);
    }
#undef CRF_STEP

    // ---- final (last EA in buffer 1):
    //      logZ_b = ln2 * (S_b + log2(sum_i EA_last[i,b])) ----
    if (tid < 256) {
        const int part = tid & 15;
        const int bb   = tid >> 4;
        const unsigned* p = reinterpret_cast<const unsigned*>(&ea[1][bb][part * 16]);
        float s = 0.f;
        #pragma unroll
        for (int w = 0; w < 4; ++w) {
            unsigned u = p[w];
            s += __builtin_amdgcn_cvt_f32_fp8((int)u, 0);
            s += __builtin_amdgcn_cvt_f32_fp8((int)u, 1);
            s += __builtin_amdgcn_cvt_f32_fp8((int)u, 2);
            s += __builtin_amdgcn_cvt_f32_fp8((int)u, 3);
        }
        sump[bb][part] = s;
    }
    __syncthreads();
    if (tid < BG) {
        float tot = 0.f;
        #pragma unroll
        for (int p = 0; p < 16; ++p) tot += sump[tid][p];
        // threads 0..15 have b == tid, so their S is batch tid's exponent sum
        lzb[tid] = (S + log2_fast(tot)) * LN2;
    }
    __syncthreads();
    if (tid == 0) {
        float p = 0.f;
        #pragma unroll
        for (int j = 0; j < BG; ++j) p += lzb[j];
        bout[blockIdx.x] = p;
    }
}

__global__ void crf_reduce(const float* __restrict__ bout, float* __restrict__ out)
{
    if (threadIdx.x == 0) {
        float s = 0.f;
        for (int j = 0; j < NWG; ++j) s += bout[j];
        out[0] = s;
    }
}

extern "C" void kernel_launch(void* const* d_in, const int* in_sizes, int n_in,
                              void* d_out, int out_size, void* d_ws, size_t ws_size,
                              hipStream_t stream)
{
    const float* emis  = (const float*)d_in[0];
    const float* trans = (const float*)d_in[1];
    const int*   words = (const int*)d_in[2];
    float* out  = (float*)d_out;
    float* bout = (float*)d_ws;   // NWG floats of scratch

    crf_forward<<<NWG, 512, 0, stream>>>(emis, trans, words, bout);
    crf_reduce<<<1, 64, 0, stream>>>(bout, out);
}